// Round 2
// baseline (572.942 us; speedup 1.0000x reference)
//
#include <hip/hip_runtime.h>

// Problem constants (B=1)
#define NN 1024     // nodes
#define NE 4096     // edges
#define FVD 512
#define FED 64
#define NHD 256
#define FOUTD 250
#define ICAP 64     // max incident edges per node (E[deg]=8, Poisson tail safe)
#define VCAP 64     // max off-diag nnz per adj_v row
#define ECAP 128    // max off-diag nnz per adj_e row (E[adj]~16)

// ---------------------------------------------------------------------------
// 1) Extract edge endpoints from dense T (N x E, <=2 nnz per column) and
//    build node->edge incidence lists (fixed capacity, atomic fill).
__global__ __launch_bounds__(256) void extract_edges(
    const float* __restrict__ T, int* __restrict__ se, int* __restrict__ te,
    int* __restrict__ inc, int* __restrict__ icnt) {
  int e = blockIdx.x * blockDim.x + threadIdx.x;
  if (e >= NE) return;
  int s = -1, t = -1;
  for (int n = 0; n < NN; n++) {
    float v = T[(size_t)n * NE + e];
    if (v > 0.5f) {
      if (v > 1.5f) { s = n; t = n; break; }   // self-loop, weight 2
      if (s < 0) { s = n; } else { t = n; break; }
    }
  }
  if (s < 0) s = 0;          // defensive (cannot happen per construction)
  if (t < 0) t = s;
  se[e] = s; te[e] = t;
  int p = atomicAdd(&icnt[s], 1);
  if (p < ICAP) inc[s * ICAP + p] = e;
  if (t != s) {
    p = atomicAdd(&icnt[t], 1);
    if (p < ICAP) inc[t * ICAP + p] = e;
  }
}

// ---------------------------------------------------------------------------
// 2) Ballot-compact dense adjacency rows into fixed-capacity CSR.
//    One wave (64 lanes) per row, float4 loads (1 KiB/wave/iter).
//    Element order within a row is elem-major interleaved — semantically
//    irrelevant (same {col,val} set; FP sum order differs from dense ref
//    regardless). Diagonal stored separately.
__global__ void compact_rows(const float* __restrict__ A, int R, int C, int cap,
                             int* __restrict__ cols, float* __restrict__ vals,
                             float* __restrict__ diag, int* __restrict__ cnt) {
  int wid = (blockIdx.x * blockDim.x + threadIdx.x) >> 6;
  int lane = threadIdx.x & 63;
  if (wid >= R) return;
  const float4* row = (const float4*)(A + (size_t)wid * C);  // C % 4 == 0
  int base = 0;
  for (int c0 = 0; c0 < C; c0 += 256) {                      // 256 cols/wave/iter
    float4 v4 = row[(c0 >> 2) + lane];
    float vv[4] = {v4.x, v4.y, v4.z, v4.w};
    #pragma unroll
    for (int j = 0; j < 4; j++) {
      int c = c0 + lane * 4 + j;
      float v = vv[j];
      if (c == wid) diag[wid] = v;
      bool pred = (v != 0.0f) && (c != wid);
      unsigned long long m = __ballot(pred);
      if (pred) {
        int idx = base + __popcll(m & ((1ull << lane) - 1ull));
        if (idx < cap) {
          cols[(size_t)wid * cap + idx] = c;
          vals[(size_t)wid * cap + idx] = v;
        }
      }
      base += __popcll(m);
    }
  }
  if (lane == 0) cnt[wid] = base < cap ? base : cap;
}

// ---------------------------------------------------------------------------
// 3) Wave-per-row dot product: out[r] = dot(X[r,:], p)
__global__ void wave_dot(const float* __restrict__ X, const float* __restrict__ p,
                         float* __restrict__ out, int rows, int D) {
  int wid = (blockIdx.x * blockDim.x + threadIdx.x) >> 6;
  int lane = threadIdx.x & 63;
  if (wid >= rows) return;
  float acc = 0.0f;
  for (int d = lane; d < D; d += 64) acc += X[(size_t)wid * D + d] * p[d];
  for (int off = 32; off; off >>= 1) acc += __shfl_down(acc, off);
  if (lane == 0) out[wid] = acc;
}

// ---------------------------------------------------------------------------
// 4) Simple fp32 tiled GEMM: C = (RELU_A ? relu(A) : A) @ B
//    32x32 tile, BK=32, 256 threads, 2x2 per thread. Bounds-checked.
template <bool RELU_A>
__global__ __launch_bounds__(256) void gemm32(const float* __restrict__ A,
                                              const float* __restrict__ B,
                                              float* __restrict__ C,
                                              int M, int N, int K) {
  __shared__ float As[32][33];
  __shared__ float Bs[32][33];
  int tid = threadIdx.x;
  int tx = tid & 15, ty = tid >> 4;
  int bm = blockIdx.y * 32, bn = blockIdx.x * 32;
  float acc00 = 0.f, acc01 = 0.f, acc10 = 0.f, acc11 = 0.f;
  for (int k0 = 0; k0 < K; k0 += 32) {
    for (int i = tid; i < 32 * 32; i += 256) {
      int r = i >> 5, c = i & 31;
      int gr = bm + r, gc = k0 + c;
      float v = (gr < M && gc < K) ? A[(size_t)gr * K + gc] : 0.f;
      if (RELU_A) v = fmaxf(v, 0.f);
      As[r][c] = v;
    }
    for (int i = tid; i < 32 * 32; i += 256) {
      int r = i >> 5, c = i & 31;
      int gr = k0 + r, gc = bn + c;
      Bs[r][c] = (gr < K && gc < N) ? B[(size_t)gr * N + gc] : 0.f;
    }
    __syncthreads();
    #pragma unroll
    for (int kk = 0; kk < 32; kk++) {
      float a0 = As[ty * 2][kk], a1 = As[ty * 2 + 1][kk];
      float b0 = Bs[kk][tx * 2], b1 = Bs[kk][tx * 2 + 1];
      acc00 += a0 * b0; acc01 += a0 * b1;
      acc10 += a1 * b0; acc11 += a1 * b1;
    }
    __syncthreads();
  }
  int r0 = bm + ty * 2, c0 = bn + tx * 2;
  if (r0 < M) {
    if (c0 < N) C[(size_t)r0 * N + c0] = acc00;
    if (c0 + 1 < N) C[(size_t)r0 * N + c0 + 1] = acc01;
  }
  if (r0 + 1 < M) {
    if (c0 < N) C[(size_t)(r0 + 1) * N + c0] = acc10;
    if (c0 + 1 < N) C[(size_t)(r0 + 1) * N + c0 + 1] = acc11;
  }
}

// ---------------------------------------------------------------------------
// 5) Node layer apply: out[n,h] = avd[n]*HW[n,h] + sum_k coef_k * HW[col_k,h] + bias[h]
//    coef(n,m) = av[n,m] * sum_{e in inc[n]} T[n,e] * v[e] * T[m,e]
template <bool RELU>
__global__ __launch_bounds__(256) void node_apply(
    const float* __restrict__ HW, int H, const float* __restrict__ v,
    const int* __restrict__ se, const int* __restrict__ te,
    const int* __restrict__ inc, const int* __restrict__ icnt,
    const int* __restrict__ avc, const float* __restrict__ avv,
    const float* __restrict__ avd, const int* __restrict__ avcnt,
    const float* __restrict__ bias, float* __restrict__ out) {
  int n = blockIdx.x;
  __shared__ float scoef[VCAP];
  __shared__ int scol[VCAP];
  int cnt = avcnt[n];
  int tid = threadIdx.x;
  if (tid < cnt) {
    int m = avc[n * VCAP + tid];
    float mult = 0.0f;
    int ic = icnt[n]; if (ic > ICAP) ic = ICAP;
    for (int k = 0; k < ic; k++) {
      int e = inc[n * ICAP + k];
      int s = se[e], t = te[e];
      float wn = (float)((s == n) + (t == n));
      float wm = (float)((s == m) + (t == m));
      mult += wn * v[e] * wm;
    }
    scoef[tid] = mult * avv[n * VCAP + tid];
    scol[tid] = m;
  }
  __syncthreads();
  float d = avd[n];
  for (int h = tid; h < H; h += 256) {
    float acc = d * HW[(size_t)n * H + h];
    for (int k = 0; k < cnt; k++)
      acc += scoef[k] * HW[(size_t)scol[k] * H + h];
    acc += bias[h];
    if (RELU) acc = fmaxf(acc, 0.0f);
    out[(size_t)n * H + h] = acc;
  }
}

// ---------------------------------------------------------------------------
// 6) Edge layer pass A: per-row coefficients + row max (== column max: A symmetric,
//    diag = ae[i,i] = 2*di^2 > 0 dominates implicit zeros)
__global__ __launch_bounds__(256) void edge_coef(
    const float* __restrict__ v2, const int* __restrict__ se, const int* __restrict__ te,
    const int* __restrict__ aec, const float* __restrict__ aev,
    const float* __restrict__ aed, const int* __restrict__ aecnt,
    float* __restrict__ coef, float* __restrict__ rmax) {
  int i = blockIdx.x * blockDim.x + threadIdx.x;
  if (i >= NE) return;
  int s = se[i], t = te[i];
  float vs = v2[s], vt = v2[t];
  int cnt = aecnt[i];
  float mx = aed[i];
  for (int k = 0; k < cnt; k++) {
    int j = aec[i * ECAP + k];
    int sj = se[j], tj = te[j];
    float m;
    if (s == t) {
      m = 2.0f * vs * (float)((sj == s) + (tj == s));
    } else {
      m = vs * (float)((sj == s) + (tj == s)) + vt * (float)((sj == t) + (tj == t));
    }
    float c = m * aev[i * ECAP + k];
    coef[i * ECAP + k] = c;
    mx = fmaxf(mx, c);
  }
  rmax[i] = mx;
}

// 7) Edge layer pass B: out[i,h] = relu( sum_j A[i,j]/colmax[j] * ZW[j,h] + b[h] )
__global__ __launch_bounds__(128) void edge_apply(
    const float* __restrict__ ZW, const int* __restrict__ aec,
    const float* __restrict__ coef, const float* __restrict__ aed,
    const int* __restrict__ aecnt, const float* __restrict__ rmax,
    const float* __restrict__ bias, float* __restrict__ out) {
  int i = blockIdx.x;
  int h = threadIdx.x;        // H == 128 == blockDim
  __shared__ float sw[ECAP];
  __shared__ int sj[ECAP];
  int cnt = aecnt[i];
  if (h < cnt) {
    int j = aec[i * ECAP + h];
    sj[h] = j;
    sw[h] = coef[i * ECAP + h] / rmax[j];
  }
  __syncthreads();
  float acc = (aed[i] / rmax[i]) * ZW[(size_t)i * 128 + h];
  for (int k = 0; k < cnt; k++)
    acc += sw[k] * ZW[(size_t)sj[k] * 128 + h];
  acc += bias[h];
  out[(size_t)i * 128 + h] = fmaxf(acc, 0.0f);
}

// ---------------------------------------------------------------------------
extern "C" void kernel_launch(void* const* d_in, const int* in_sizes, int n_in,
                              void* d_out, int out_size, void* d_ws, size_t ws_size,
                              hipStream_t stream) {
  const float* X    = (const float*)d_in[0];
  const float* Z    = (const float*)d_in[1];
  const float* adjE = (const float*)d_in[2];
  const float* adjV = (const float*)d_in[3];
  const float* T    = (const float*)d_in[4];
  const float* w1   = (const float*)d_in[5];
  const float* p1   = (const float*)d_in[6];
  const float* b1   = (const float*)d_in[7];
  const float* w2   = (const float*)d_in[8];
  const float* p2   = (const float*)d_in[9];
  const float* b2   = (const float*)d_in[10];
  const float* w3   = (const float*)d_in[11];
  const float* p3   = (const float*)d_in[12];
  const float* b3   = (const float*)d_in[13];

  float* xout = (float*)d_out;                 // (1024, 250)
  float* zout = xout + (size_t)NN * FOUTD;     // (4096, 128)

  // workspace carve-up (256B aligned)
  char* w = (char*)d_ws;
  auto alloc = [&](size_t bytes) {
    char* p = w;
    w += (bytes + 255) & ~(size_t)255;
    return p;
  };
  int*   se    = (int*)alloc(NE * 4);
  int*   te    = (int*)alloc(NE * 4);
  int*   icnt  = (int*)alloc(NN * 4);
  int*   inc   = (int*)alloc((size_t)NN * ICAP * 4);
  int*   avc   = (int*)alloc((size_t)NN * VCAP * 4);
  float* avv   = (float*)alloc((size_t)NN * VCAP * 4);
  float* avd   = (float*)alloc(NN * 4);
  int*   avcnt = (int*)alloc(NN * 4);
  int*   aec   = (int*)alloc((size_t)NE * ECAP * 4);
  float* aev   = (float*)alloc((size_t)NE * ECAP * 4);
  float* aed   = (float*)alloc(NE * 4);
  int*   aecnt = (int*)alloc(NE * 4);
  float* coef2 = (float*)alloc((size_t)NE * ECAP * 4);
  float* rmax  = (float*)alloc(NE * 4);
  float* v1    = (float*)alloc(NE * 4);
  float* v2    = (float*)alloc(NN * 4);
  float* v3    = (float*)alloc(NE * 4);
  float* HW1   = (float*)alloc((size_t)NN * NHD * 4);
  float* x1    = (float*)alloc((size_t)NN * NHD * 4);
  float* ZW2   = (float*)alloc((size_t)NE * 128 * 4);
  float* XW3   = (float*)alloc((size_t)NN * FOUTD * 4);
  (void)ws_size; (void)in_sizes; (void)n_in; (void)out_size;

  hipMemsetAsync(icnt, 0, NN * 4, stream);

  // structure extraction
  extract_edges<<<NE / 256, 256, 0, stream>>>(T, se, te, inc, icnt);
  compact_rows<<<NN * 64 / 256, 256, 0, stream>>>(adjV, NN, NN, VCAP, avc, avv, avd, avcnt);
  compact_rows<<<NE * 64 / 256, 256, 0, stream>>>(adjE, NE, NE, ECAP, aec, aev, aed, aecnt);

  // ---- layer 1 (node) ----
  wave_dot<<<NE * 64 / 256, 256, 0, stream>>>(Z, p1, v1, NE, FED);
  {
    dim3 g((NHD + 31) / 32, (NN + 31) / 32);
    gemm32<false><<<g, 256, 0, stream>>>(X, w1, HW1, NN, NHD, FVD);
  }
  node_apply<true><<<NN, 256, 0, stream>>>(HW1, NHD, v1, se, te, inc, icnt,
                                           avc, avv, avd, avcnt, b1, x1);

  // ---- layer 2 (edge) ----
  wave_dot<<<NN * 64 / 256, 256, 0, stream>>>(x1, p2, v2, NN, NHD);
  {
    dim3 g((128 + 31) / 32, (NE + 31) / 32);
    gemm32<true><<<g, 256, 0, stream>>>(Z, w2, ZW2, NE, 128, FED);  // relu(Z) @ w2
  }
  edge_coef<<<NE / 256, 256, 0, stream>>>(v2, se, te, aec, aev, aed, aecnt, coef2, rmax);
  edge_apply<<<NE, 128, 0, stream>>>(ZW2, aec, coef2, aed, aecnt, rmax, b2, zout);

  // ---- layer 3 (node) ----
  wave_dot<<<NE * 64 / 256, 256, 0, stream>>>(zout, p3, v3, NE, 128);
  {
    dim3 g((FOUTD + 31) / 32, (NN + 31) / 32);
    gemm32<false><<<g, 256, 0, stream>>>(x1, w3, XW3, NN, FOUTD, NHD);
  }
  node_apply<false><<<NN, 256, 0, stream>>>(XW3, FOUTD, v3, se, te, inc, icnt,
                                            avc, avv, avd, avcnt, b3, xout);
}

// Round 5
// 308.179 us; speedup vs baseline: 1.8591x; 1.8591x over previous
//
#include <hip/hip_runtime.h>

// Problem constants (B=1)
#define NN 1024     // nodes
#define NE 4096     // edges
#define FVD 512
#define FED 64
#define NHD 256
#define FOUTD 250
#define ICAP 64     // max incident edges per node (E[deg]=8, Poisson tail safe)
#define VCAP 64     // max off-diag nnz per adj_v row
#define ECAP 128    // max off-diag nnz per adj_e row (E[adj]~16)

// ---------------------------------------------------------------------------
// 1a) Scan all of T in parallel: one thread per (n,e) entry, coalesced along e.
//     Column e has exactly two 1.0 entries (endpoints) or one 2.0 (self-loop).
//     atomicMin/atomicMax give deterministic endpoints (order irrelevant:
//     all downstream math is symmetric in (s,t)).
__global__ __launch_bounds__(256) void scan_T(
    const float* __restrict__ T, int* __restrict__ se, int* __restrict__ te) {
  size_t i = (size_t)blockIdx.x * blockDim.x + threadIdx.x;   // i = n*NE + e
  if (i >= (size_t)NN * NE) return;
  float v = T[i];
  if (v > 0.5f) {
    int n = (int)(i >> 12);        // / NE
    int e = (int)(i & (NE - 1));   // % NE
    atomicMin(&se[e], n);
    atomicMax(&te[e], n);
  }
}

// 1b) Build node->edge incidence lists from endpoints.
__global__ __launch_bounds__(256) void build_inc(
    int* __restrict__ se, int* __restrict__ te,
    int* __restrict__ inc, int* __restrict__ icnt) {
  int e = blockIdx.x * blockDim.x + threadIdx.x;
  if (e >= NE) return;
  int s = se[e], t = te[e];
  if (s < 0 || s >= NN) { s = 0; se[e] = 0; }   // defensive
  if (t < 0 || t >= NN) { t = s; te[e] = s; }
  int p = atomicAdd(&icnt[s], 1);
  if (p < ICAP) inc[s * ICAP + p] = e;
  if (t != s) {
    p = atomicAdd(&icnt[t], 1);
    if (p < ICAP) inc[t * ICAP + p] = e;
  }
}

// ---------------------------------------------------------------------------
// 2) Ballot-compact dense adjacency rows into fixed-capacity CSR.
//    One wave (64 lanes) per row, float4 loads (1 KiB/wave/iter).
__global__ void compact_rows(const float* __restrict__ A, int R, int C, int cap,
                             int* __restrict__ cols, float* __restrict__ vals,
                             float* __restrict__ diag, int* __restrict__ cnt) {
  int wid = (blockIdx.x * blockDim.x + threadIdx.x) >> 6;
  int lane = threadIdx.x & 63;
  if (wid >= R) return;
  const float4* row = (const float4*)(A + (size_t)wid * C);  // C % 4 == 0
  int base = 0;
  for (int c0 = 0; c0 < C; c0 += 256) {                      // 256 cols/wave/iter
    float4 v4 = row[(c0 >> 2) + lane];
    float vv[4] = {v4.x, v4.y, v4.z, v4.w};
    #pragma unroll
    for (int j = 0; j < 4; j++) {
      int c = c0 + lane * 4 + j;
      float v = vv[j];
      if (c == wid) diag[wid] = v;
      bool pred = (v != 0.0f) && (c != wid);
      unsigned long long m = __ballot(pred);
      if (pred) {
        int idx = base + __popcll(m & ((1ull << lane) - 1ull));
        if (idx < cap) {
          cols[(size_t)wid * cap + idx] = c;
          vals[(size_t)wid * cap + idx] = v;
        }
      }
      base += __popcll(m);
    }
  }
  if (lane == 0) cnt[wid] = base < cap ? base : cap;
}

// ---------------------------------------------------------------------------
// 3) Wave-per-row dot product: out[r] = dot(X[r,:], p)
__global__ void wave_dot(const float* __restrict__ X, const float* __restrict__ p,
                         float* __restrict__ out, int rows, int D) {
  int wid = (blockIdx.x * blockDim.x + threadIdx.x) >> 6;
  int lane = threadIdx.x & 63;
  if (wid >= rows) return;
  float acc = 0.0f;
  for (int d = lane; d < D; d += 64) acc += X[(size_t)wid * D + d] * p[d];
  for (int off = 32; off; off >>= 1) acc += __shfl_down(acc, off);
  if (lane == 0) out[wid] = acc;
}

// ---------------------------------------------------------------------------
// 4) Simple fp32 tiled GEMM: C = (RELU_A ? relu(A) : A) @ B
template <bool RELU_A>
__global__ __launch_bounds__(256) void gemm32(const float* __restrict__ A,
                                              const float* __restrict__ B,
                                              float* __restrict__ C,
                                              int M, int N, int K) {
  __shared__ float As[32][33];
  __shared__ float Bs[32][33];
  int tid = threadIdx.x;
  int tx = tid & 15, ty = tid >> 4;
  int bm = blockIdx.y * 32, bn = blockIdx.x * 32;
  float acc00 = 0.f, acc01 = 0.f, acc10 = 0.f, acc11 = 0.f;
  for (int k0 = 0; k0 < K; k0 += 32) {
    for (int i = tid; i < 32 * 32; i += 256) {
      int r = i >> 5, c = i & 31;
      int gr = bm + r, gc = k0 + c;
      float v = (gr < M && gc < K) ? A[(size_t)gr * K + gc] : 0.f;
      if (RELU_A) v = fmaxf(v, 0.f);
      As[r][c] = v;
    }
    for (int i = tid; i < 32 * 32; i += 256) {
      int r = i >> 5, c = i & 31;
      int gr = k0 + r, gc = bn + c;
      Bs[r][c] = (gr < K && gc < N) ? B[(size_t)gr * N + gc] : 0.f;
    }
    __syncthreads();
    #pragma unroll
    for (int kk = 0; kk < 32; kk++) {
      float a0 = As[ty * 2][kk], a1 = As[ty * 2 + 1][kk];
      float b0 = Bs[kk][tx * 2], b1 = Bs[kk][tx * 2 + 1];
      acc00 += a0 * b0; acc01 += a0 * b1;
      acc10 += a1 * b0; acc11 += a1 * b1;
    }
    __syncthreads();
  }
  int r0 = bm + ty * 2, c0 = bn + tx * 2;
  if (r0 < M) {
    if (c0 < N) C[(size_t)r0 * N + c0] = acc00;
    if (c0 + 1 < N) C[(size_t)r0 * N + c0 + 1] = acc01;
  }
  if (r0 + 1 < M) {
    if (c0 < N) C[(size_t)(r0 + 1) * N + c0] = acc10;
    if (c0 + 1 < N) C[(size_t)(r0 + 1) * N + c0 + 1] = acc11;
  }
}

// ---------------------------------------------------------------------------
// 5) Node layer apply
template <bool RELU>
__global__ __launch_bounds__(256) void node_apply(
    const float* __restrict__ HW, int H, const float* __restrict__ v,
    const int* __restrict__ se, const int* __restrict__ te,
    const int* __restrict__ inc, const int* __restrict__ icnt,
    const int* __restrict__ avc, const float* __restrict__ avv,
    const float* __restrict__ avd, const int* __restrict__ avcnt,
    const float* __restrict__ bias, float* __restrict__ out) {
  int n = blockIdx.x;
  __shared__ float scoef[VCAP];
  __shared__ int scol[VCAP];
  int cnt = avcnt[n];
  int tid = threadIdx.x;
  if (tid < cnt) {
    int m = avc[n * VCAP + tid];
    float mult = 0.0f;
    int ic = icnt[n]; if (ic > ICAP) ic = ICAP;
    for (int k = 0; k < ic; k++) {
      int e = inc[n * ICAP + k];
      int s = se[e], t = te[e];
      float wn = (float)((s == n) + (t == n));
      float wm = (float)((s == m) + (t == m));
      mult += wn * v[e] * wm;
    }
    scoef[tid] = mult * avv[n * VCAP + tid];
    scol[tid] = m;
  }
  __syncthreads();
  float d = avd[n];
  for (int h = tid; h < H; h += 256) {
    float acc = d * HW[(size_t)n * H + h];
    for (int k = 0; k < cnt; k++)
      acc += scoef[k] * HW[(size_t)scol[k] * H + h];
    acc += bias[h];
    if (RELU) acc = fmaxf(acc, 0.0f);
    out[(size_t)n * H + h] = acc;
  }
}

// ---------------------------------------------------------------------------
// 6) Edge layer pass A: per-row coefficients + row max (== column max: A symmetric,
//    diag = ae[i,i] > 0 dominates implicit zeros)
__global__ __launch_bounds__(256) void edge_coef(
    const float* __restrict__ v2, const int* __restrict__ se, const int* __restrict__ te,
    const int* __restrict__ aec, const float* __restrict__ aev,
    const float* __restrict__ aed, const int* __restrict__ aecnt,
    float* __restrict__ coef, float* __restrict__ rmax) {
  int i = blockIdx.x * blockDim.x + threadIdx.x;
  if (i >= NE) return;
  int s = se[i], t = te[i];
  float vs = v2[s], vt = v2[t];
  int cnt = aecnt[i];
  float mx = aed[i];
  for (int k = 0; k < cnt; k++) {
    int j = aec[i * ECAP + k];
    int sj = se[j], tj = te[j];
    float m;
    if (s == t) {
      m = 2.0f * vs * (float)((sj == s) + (tj == s));
    } else {
      m = vs * (float)((sj == s) + (tj == s)) + vt * (float)((sj == t) + (tj == t));
    }
    float c = m * aev[i * ECAP + k];
    coef[i * ECAP + k] = c;
    mx = fmaxf(mx, c);
  }
  rmax[i] = mx;
}

// 7) Edge layer pass B
__global__ __launch_bounds__(128) void edge_apply(
    const float* __restrict__ ZW, const int* __restrict__ aec,
    const float* __restrict__ coef, const float* __restrict__ aed,
    const int* __restrict__ aecnt, const float* __restrict__ rmax,
    const float* __restrict__ bias, float* __restrict__ out) {
  int i = blockIdx.x;
  int h = threadIdx.x;        // H == 128 == blockDim
  __shared__ float sw[ECAP];
  __shared__ int sj[ECAP];
  int cnt = aecnt[i];
  if (h < cnt) {
    int j = aec[i * ECAP + h];
    sj[h] = j;
    sw[h] = coef[i * ECAP + h] / rmax[j];
  }
  __syncthreads();
  float acc = (aed[i] / rmax[i]) * ZW[(size_t)i * 128 + h];
  for (int k = 0; k < cnt; k++)
    acc += sw[k] * ZW[(size_t)sj[k] * 128 + h];
  acc += bias[h];
  out[(size_t)i * 128 + h] = fmaxf(acc, 0.0f);
}

// ---------------------------------------------------------------------------
extern "C" void kernel_launch(void* const* d_in, const int* in_sizes, int n_in,
                              void* d_out, int out_size, void* d_ws, size_t ws_size,
                              hipStream_t stream) {
  const float* X    = (const float*)d_in[0];
  const float* Z    = (const float*)d_in[1];
  const float* adjE = (const float*)d_in[2];
  const float* adjV = (const float*)d_in[3];
  const float* T    = (const float*)d_in[4];
  const float* w1   = (const float*)d_in[5];
  const float* p1   = (const float*)d_in[6];
  const float* b1   = (const float*)d_in[7];
  const float* w2   = (const float*)d_in[8];
  const float* p2   = (const float*)d_in[9];
  const float* b2   = (const float*)d_in[10];
  const float* w3   = (const float*)d_in[11];
  const float* p3   = (const float*)d_in[12];
  const float* b3   = (const float*)d_in[13];

  float* xout = (float*)d_out;                 // (1024, 250)
  float* zout = xout + (size_t)NN * FOUTD;     // (4096, 128)

  // workspace carve-up (256B aligned)
  char* w = (char*)d_ws;
  auto alloc = [&](size_t bytes) {
    char* p = w;
    w += (bytes + 255) & ~(size_t)255;
    return p;
  };
  int*   se    = (int*)alloc(NE * 4);
  int*   te    = (int*)alloc(NE * 4);
  int*   icnt  = (int*)alloc(NN * 4);
  int*   inc   = (int*)alloc((size_t)NN * ICAP * 4);
  int*   avc   = (int*)alloc((size_t)NN * VCAP * 4);
  float* avv   = (float*)alloc((size_t)NN * VCAP * 4);
  float* avd   = (float*)alloc(NN * 4);
  int*   avcnt = (int*)alloc(NN * 4);
  int*   aec   = (int*)alloc((size_t)NE * ECAP * 4);
  float* aev   = (float*)alloc((size_t)NE * ECAP * 4);
  float* aed   = (float*)alloc(NE * 4);
  int*   aecnt = (int*)alloc(NE * 4);
  float* coef2 = (float*)alloc((size_t)NE * ECAP * 4);
  float* rmax  = (float*)alloc(NE * 4);
  float* v1    = (float*)alloc(NE * 4);
  float* v2    = (float*)alloc(NN * 4);
  float* v3    = (float*)alloc(NE * 4);
  float* HW1   = (float*)alloc((size_t)NN * NHD * 4);
  float* x1    = (float*)alloc((size_t)NN * NHD * 4);
  float* ZW2   = (float*)alloc((size_t)NE * 128 * 4);
  float* XW3   = (float*)alloc((size_t)NN * FOUTD * 4);
  (void)ws_size; (void)in_sizes; (void)n_in; (void)out_size;

  hipMemsetAsync(icnt, 0, NN * 4, stream);
  hipMemsetAsync(se, 0x7f, NE * 4, stream);    // ~INT_MAX for atomicMin
  hipMemsetAsync(te, 0xff, NE * 4, stream);    // -1 for atomicMax

  // structure extraction (full-GPU parallel scan of T)
  scan_T<<<(NN * NE) / 256, 256, 0, stream>>>(T, se, te);
  build_inc<<<NE / 256, 256, 0, stream>>>(se, te, inc, icnt);
  compact_rows<<<NN * 64 / 256, 256, 0, stream>>>(adjV, NN, NN, VCAP, avc, avv, avd, avcnt);
  compact_rows<<<NE * 64 / 256, 256, 0, stream>>>(adjE, NE, NE, ECAP, aec, aev, aed, aecnt);

  // ---- layer 1 (node) ----
  wave_dot<<<NE * 64 / 256, 256, 0, stream>>>(Z, p1, v1, NE, FED);
  {
    dim3 g((NHD + 31) / 32, (NN + 31) / 32);
    gemm32<false><<<g, 256, 0, stream>>>(X, w1, HW1, NN, NHD, FVD);
  }
  node_apply<true><<<NN, 256, 0, stream>>>(HW1, NHD, v1, se, te, inc, icnt,
                                           avc, avv, avd, avcnt, b1, x1);

  // ---- layer 2 (edge) ----
  wave_dot<<<NN * 64 / 256, 256, 0, stream>>>(x1, p2, v2, NN, NHD);
  {
    dim3 g((128 + 31) / 32, (NE + 31) / 32);
    gemm32<true><<<g, 256, 0, stream>>>(Z, w2, ZW2, NE, 128, FED);  // relu(Z) @ w2
  }
  edge_coef<<<NE / 256, 256, 0, stream>>>(v2, se, te, aec, aev, aed, aecnt, coef2, rmax);
  edge_apply<<<NE, 128, 0, stream>>>(ZW2, aec, coef2, aed, aecnt, rmax, b2, zout);

  // ---- layer 3 (node) ----
  wave_dot<<<NE * 64 / 256, 256, 0, stream>>>(zout, p3, v3, NE, 128);
  {
    dim3 g((FOUTD + 31) / 32, (NN + 31) / 32);
    gemm32<false><<<g, 256, 0, stream>>>(x1, w3, XW3, NN, FOUTD, NHD);
  }
  node_apply<false><<<NN, 256, 0, stream>>>(XW3, FOUTD, v3, se, te, inc, icnt,
                                            avc, avv, avd, avcnt, b3, xout);
}

// Round 10
// 266.394 us; speedup vs baseline: 2.1507x; 1.1569x over previous
//
#include <hip/hip_runtime.h>

// Problem constants (B=1)
#define NN 1024     // nodes
#define NE 4096     // edges
#define FVD 512
#define FED 64
#define NHD 256
#define FOUTD 250
#define ICAP 64     // max incident edges per node (E[deg]=8, Poisson tail safe)
#define VCAP 64     // max off-diag nnz per adj_v row
#define ECAP 128    // max off-diag nnz per adj_e row (E[adj]~16)

// ---------------------------------------------------------------------------
// 1a) Scan all of T in parallel: one thread per (n,e) entry, coalesced along e.
__global__ __launch_bounds__(256) void scan_T(
    const float* __restrict__ T, int* __restrict__ se, int* __restrict__ te) {
  size_t i = (size_t)blockIdx.x * blockDim.x + threadIdx.x;   // i = n*NE + e
  if (i >= (size_t)NN * NE) return;
  float v = T[i];
  if (v > 0.5f) {
    int n = (int)(i >> 12);        // / NE
    int e = (int)(i & (NE - 1));   // % NE
    atomicMin(&se[e], n);
    atomicMax(&te[e], n);
  }
}

// 1b) Build node->edge incidence lists from endpoints.
__global__ __launch_bounds__(256) void build_inc(
    int* __restrict__ se, int* __restrict__ te,
    int* __restrict__ inc, int* __restrict__ icnt) {
  int e = blockIdx.x * blockDim.x + threadIdx.x;
  if (e >= NE) return;
  int s = se[e], t = te[e];
  if (s < 0 || s >= NN) { s = 0; se[e] = 0; }   // defensive
  if (t < 0 || t >= NN) { t = s; te[e] = s; }
  int p = atomicAdd(&icnt[s], 1);
  if (p < ICAP) inc[s * ICAP + p] = e;
  if (t != s) {
    p = atomicAdd(&icnt[t], 1);
    if (p < ICAP) inc[t * ICAP + p] = e;
  }
}

// ---------------------------------------------------------------------------
// 2) Ballot-compact dense adjacency rows into fixed-capacity CSR.
__global__ void compact_rows(const float* __restrict__ A, int R, int C, int cap,
                             int* __restrict__ cols, float* __restrict__ vals,
                             float* __restrict__ diag, int* __restrict__ cnt) {
  int wid = (blockIdx.x * blockDim.x + threadIdx.x) >> 6;
  int lane = threadIdx.x & 63;
  if (wid >= R) return;
  const float4* row = (const float4*)(A + (size_t)wid * C);  // C % 4 == 0
  int base = 0;
  for (int c0 = 0; c0 < C; c0 += 256) {                      // 256 cols/wave/iter
    float4 v4 = row[(c0 >> 2) + lane];
    float vv[4] = {v4.x, v4.y, v4.z, v4.w};
    #pragma unroll
    for (int j = 0; j < 4; j++) {
      int c = c0 + lane * 4 + j;
      float v = vv[j];
      if (c == wid) diag[wid] = v;
      bool pred = (v != 0.0f) && (c != wid);
      unsigned long long m = __ballot(pred);
      if (pred) {
        int idx = base + __popcll(m & ((1ull << lane) - 1ull));
        if (idx < cap) {
          cols[(size_t)wid * cap + idx] = c;
          vals[(size_t)wid * cap + idx] = v;
        }
      }
      base += __popcll(m);
    }
  }
  if (lane == 0) cnt[wid] = base < cap ? base : cap;
}

// ---------------------------------------------------------------------------
// 3) Wave-per-row dot product: out[r] = dot(X[r,:], p)
__global__ void wave_dot(const float* __restrict__ X, const float* __restrict__ p,
                         float* __restrict__ out, int rows, int D) {
  int wid = (blockIdx.x * blockDim.x + threadIdx.x) >> 6;
  int lane = threadIdx.x & 63;
  if (wid >= rows) return;
  float acc = 0.0f;
  for (int d = lane; d < D; d += 64) acc += X[(size_t)wid * D + d] * p[d];
  for (int off = 32; off; off >>= 1) acc += __shfl_down(acc, off);
  if (lane == 0) out[wid] = acc;
}

// ---------------------------------------------------------------------------
// 4) Register-blocked LDS-free split-K GEMM.
//    Cpart[ks][m][n] = (RELU_A?relu(A):A)[m, ks-slice] @ B[ks-slice, n]
//    Thread: 4 cols (float4) x RPT=4 rows; 64 FMA per 8 vector loads.
//    Each (blockIdx.x, ks) fully owns its partial rows -> plain stores,
//    no init, no atomics, deterministic.
template <bool RELU_A, int N4, int KK, int KSPLIT>
__global__ __launch_bounds__(256) void gemm_f4(
    const float* __restrict__ A, const float* __restrict__ B,
    float* __restrict__ Cpart, int M) {
  constexpr int RPT = 4;
  constexpr int RG = 256 / N4;          // row-groups per block
  constexpr int KPS = KK / KSPLIT;      // k per slice
  int tid = threadIdx.x;
  int c4 = tid % N4;
  int rg = tid / N4;
  int ks = blockIdx.y;
  int m0 = blockIdx.x * (RG * RPT) + rg * RPT;
  const float4* B4 = (const float4*)B;
  float4 acc[RPT];
  #pragma unroll
  for (int r = 0; r < RPT; r++) acc[r] = make_float4(0.f, 0.f, 0.f, 0.f);
  int kbeg = ks * KPS;
  #pragma unroll 4
  for (int kc = 0; kc < KPS; kc += 4) {
    int k = kbeg + kc;
    float4 b0 = B4[(size_t)(k + 0) * N4 + c4];
    float4 b1 = B4[(size_t)(k + 1) * N4 + c4];
    float4 b2 = B4[(size_t)(k + 2) * N4 + c4];
    float4 b3 = B4[(size_t)(k + 3) * N4 + c4];
    #pragma unroll
    for (int r = 0; r < RPT; r++) {
      float4 a = *(const float4*)(A + (size_t)(m0 + r) * KK + k);
      if (RELU_A) {
        a.x = fmaxf(a.x, 0.f); a.y = fmaxf(a.y, 0.f);
        a.z = fmaxf(a.z, 0.f); a.w = fmaxf(a.w, 0.f);
      }
      acc[r].x += a.x * b0.x; acc[r].y += a.x * b0.y; acc[r].z += a.x * b0.z; acc[r].w += a.x * b0.w;
      acc[r].x += a.y * b1.x; acc[r].y += a.y * b1.y; acc[r].z += a.y * b1.z; acc[r].w += a.y * b1.w;
      acc[r].x += a.z * b2.x; acc[r].y += a.z * b2.y; acc[r].z += a.z * b2.z; acc[r].w += a.z * b2.w;
      acc[r].x += a.w * b3.x; acc[r].y += a.w * b3.y; acc[r].z += a.w * b3.z; acc[r].w += a.w * b3.w;
    }
  }
  float4* out = (float4*)Cpart + ((size_t)ks * M + m0) * N4 + c4;
  #pragma unroll
  for (int r = 0; r < RPT; r++) out[(size_t)r * N4] = acc[r];
}

// 4b) Sum KSPLIT partial slabs: out[i] = sum_ks part[ks][i]  (float4 elems)
__global__ void reduce_part(const float4* __restrict__ part, float4* __restrict__ out,
                            int n4, int ksplit) {
  int i = blockIdx.x * blockDim.x + threadIdx.x;
  int stride = gridDim.x * blockDim.x;
  for (; i < n4; i += stride) {
    float4 s = part[i];
    for (int k = 1; k < ksplit; k++) {
      float4 p = part[(size_t)k * n4 + i];
      s.x += p.x; s.y += p.y; s.z += p.z; s.w += p.w;
    }
    out[i] = s;
  }
}

// 4c) Pad w3 (256 x 250) into w3p (256 x 256), zeros in cols 250..255.
__global__ void pad_w3(const float* __restrict__ w3, float* __restrict__ w3p) {
  int i = blockIdx.x * blockDim.x + threadIdx.x;   // over 256*256
  if (i >= 256 * 256) return;
  int r = i >> 8, c = i & 255;
  w3p[i] = (c < FOUTD) ? w3[r * FOUTD + c] : 0.f;
}

// ---------------------------------------------------------------------------
// 5) Node layer apply: out[n,h] = avd[n]*HW[n,h] + sum_k coef_k*HW[col_k,h] + b[h]
//    HW has row-stride ldH (padded); out has row-stride H.
template <bool RELU>
__global__ __launch_bounds__(256) void node_apply(
    const float* __restrict__ HW, int H, int ldH, const float* __restrict__ v,
    const int* __restrict__ se, const int* __restrict__ te,
    const int* __restrict__ inc, const int* __restrict__ icnt,
    const int* __restrict__ avc, const float* __restrict__ avv,
    const float* __restrict__ avd, const int* __restrict__ avcnt,
    const float* __restrict__ bias, float* __restrict__ out) {
  int n = blockIdx.x;
  __shared__ float scoef[VCAP];
  __shared__ int scol[VCAP];
  int cnt = avcnt[n];
  int tid = threadIdx.x;
  if (tid < cnt) {
    int m = avc[n * VCAP + tid];
    float mult = 0.0f;
    int ic = icnt[n]; if (ic > ICAP) ic = ICAP;
    for (int k = 0; k < ic; k++) {
      int e = inc[n * ICAP + k];
      int s = se[e], t = te[e];
      float wn = (float)((s == n) + (t == n));
      float wm = (float)((s == m) + (t == m));
      mult += wn * v[e] * wm;
    }
    scoef[tid] = mult * avv[n * VCAP + tid];
    scol[tid] = m;
  }
  __syncthreads();
  float d = avd[n];
  for (int h = tid; h < H; h += 256) {
    float acc = d * HW[(size_t)n * ldH + h];
    for (int k = 0; k < cnt; k++)
      acc += scoef[k] * HW[(size_t)scol[k] * ldH + h];
    acc += bias[h];
    if (RELU) acc = fmaxf(acc, 0.0f);
    out[(size_t)n * H + h] = acc;
  }
}

// ---------------------------------------------------------------------------
// 6) Edge layer pass A: per-row coefficients + row max (== column max: A symmetric,
//    diag = ae[i,i] > 0 dominates implicit zeros)
__global__ __launch_bounds__(256) void edge_coef(
    const float* __restrict__ v2, const int* __restrict__ se, const int* __restrict__ te,
    const int* __restrict__ aec, const float* __restrict__ aev,
    const float* __restrict__ aed, const int* __restrict__ aecnt,
    float* __restrict__ coef, float* __restrict__ rmax) {
  int i = blockIdx.x * blockDim.x + threadIdx.x;
  if (i >= NE) return;
  int s = se[i], t = te[i];
  float vs = v2[s], vt = v2[t];
  int cnt = aecnt[i];
  float mx = aed[i];
  for (int k = 0; k < cnt; k++) {
    int j = aec[i * ECAP + k];
    int sj = se[j], tj = te[j];
    float m;
    if (s == t) {
      m = 2.0f * vs * (float)((sj == s) + (tj == s));
    } else {
      m = vs * (float)((sj == s) + (tj == s)) + vt * (float)((sj == t) + (tj == t));
    }
    float c = m * aev[i * ECAP + k];
    coef[i * ECAP + k] = c;
    mx = fmaxf(mx, c);
  }
  rmax[i] = mx;
}

// 7) Edge layer pass B
__global__ __launch_bounds__(128) void edge_apply(
    const float* __restrict__ ZW, const int* __restrict__ aec,
    const float* __restrict__ coef, const float* __restrict__ aed,
    const int* __restrict__ aecnt, const float* __restrict__ rmax,
    const float* __restrict__ bias, float* __restrict__ out) {
  int i = blockIdx.x;
  int h = threadIdx.x;        // H == 128 == blockDim
  __shared__ float sw[ECAP];
  __shared__ int sj[ECAP];
  int cnt = aecnt[i];
  if (h < cnt) {
    int j = aec[i * ECAP + h];
    sj[h] = j;
    sw[h] = coef[i * ECAP + h] / rmax[j];
  }
  __syncthreads();
  float acc = (aed[i] / rmax[i]) * ZW[(size_t)i * 128 + h];
  for (int k = 0; k < cnt; k++)
    acc += sw[k] * ZW[(size_t)sj[k] * 128 + h];
  acc += bias[h];
  out[(size_t)i * 128 + h] = fmaxf(acc, 0.0f);
}

// ---------------------------------------------------------------------------
extern "C" void kernel_launch(void* const* d_in, const int* in_sizes, int n_in,
                              void* d_out, int out_size, void* d_ws, size_t ws_size,
                              hipStream_t stream) {
  const float* X    = (const float*)d_in[0];
  const float* Z    = (const float*)d_in[1];
  const float* adjE = (const float*)d_in[2];
  const float* adjV = (const float*)d_in[3];
  const float* T    = (const float*)d_in[4];
  const float* w1   = (const float*)d_in[5];
  const float* p1   = (const float*)d_in[6];
  const float* b1   = (const float*)d_in[7];
  const float* w2   = (const float*)d_in[8];
  const float* p2   = (const float*)d_in[9];
  const float* b2   = (const float*)d_in[10];
  const float* w3   = (const float*)d_in[11];
  const float* p3   = (const float*)d_in[12];
  const float* b3   = (const float*)d_in[13];

  float* xout = (float*)d_out;                 // (1024, 250)
  float* zout = xout + (size_t)NN * FOUTD;     // (4096, 128)

  // workspace carve-up (256B aligned)
  char* w = (char*)d_ws;
  auto alloc = [&](size_t bytes) {
    char* p = w;
    w += (bytes + 255) & ~(size_t)255;
    return p;
  };
  int*   se    = (int*)alloc(NE * 4);
  int*   te    = (int*)alloc(NE * 4);
  int*   icnt  = (int*)alloc(NN * 4);
  int*   inc   = (int*)alloc((size_t)NN * ICAP * 4);
  int*   avc   = (int*)alloc((size_t)NN * VCAP * 4);
  float* avv   = (float*)alloc((size_t)NN * VCAP * 4);
  float* avd   = (float*)alloc(NN * 4);
  int*   avcnt = (int*)alloc(NN * 4);
  int*   aec   = (int*)alloc((size_t)NE * ECAP * 4);
  float* aev   = (float*)alloc((size_t)NE * ECAP * 4);
  float* aed   = (float*)alloc(NE * 4);
  int*   aecnt = (int*)alloc(NE * 4);
  float* coef2 = (float*)alloc((size_t)NE * ECAP * 4);
  float* rmax  = (float*)alloc(NE * 4);
  float* v1    = (float*)alloc(NE * 4);
  float* v2    = (float*)alloc(NN * 4);
  float* v3    = (float*)alloc(NE * 4);
  float* HW1   = (float*)alloc((size_t)NN * NHD * 4);        // 1 MB
  float* x1    = (float*)alloc((size_t)NN * NHD * 4);        // 1 MB
  float* ZW2   = (float*)alloc((size_t)NE * 128 * 4);        // 2 MB
  float* XW3p  = (float*)alloc((size_t)NN * 256 * 4);        // 1 MB (stride 256)
  float* w3p   = (float*)alloc(256 * 256 * 4);               // padded w3
  float* gpart = (float*)alloc((size_t)8 * NN * NHD * 4);    // 8 MB shared split-K slab
  (void)ws_size; (void)in_sizes; (void)n_in; (void)out_size;

  hipMemsetAsync(icnt, 0, NN * 4, stream);
  hipMemsetAsync(se, 0x7f, NE * 4, stream);    // ~INT_MAX for atomicMin
  hipMemsetAsync(te, 0xff, NE * 4, stream);    // -1 for atomicMax

  // structure extraction (full-GPU parallel scan of T)
  scan_T<<<(NN * NE) / 256, 256, 0, stream>>>(T, se, te);
  build_inc<<<NE / 256, 256, 0, stream>>>(se, te, inc, icnt);
  compact_rows<<<NN * 64 / 256, 256, 0, stream>>>(adjV, NN, NN, VCAP, avc, avv, avd, avcnt);
  compact_rows<<<NE * 64 / 256, 256, 0, stream>>>(adjE, NE, NE, ECAP, aec, aev, aed, aecnt);
  pad_w3<<<256, 256, 0, stream>>>(w3, w3p);

  // ---- layer 1 (node): HW1 = X @ w1 ----
  wave_dot<<<NE * 64 / 256, 256, 0, stream>>>(Z, p1, v1, NE, FED);
  gemm_f4<false, 64, 512, 8><<<dim3(64, 8), 256, 0, stream>>>(X, w1, gpart, NN);
  reduce_part<<<512, 256, 0, stream>>>((const float4*)gpart, (float4*)HW1,
                                       NN * NHD / 4, 8);
  node_apply<true><<<NN, 256, 0, stream>>>(HW1, NHD, NHD, v1, se, te, inc, icnt,
                                           avc, avv, avd, avcnt, b1, x1);

  // ---- layer 2 (edge): ZW2 = relu(Z) @ w2 ----
  wave_dot<<<NN * 64 / 256, 256, 0, stream>>>(x1, p2, v2, NN, NHD);
  gemm_f4<true, 32, 64, 4><<<dim3(128, 4), 256, 0, stream>>>(Z, w2, gpart, NE);
  reduce_part<<<512, 256, 0, stream>>>((const float4*)gpart, (float4*)ZW2,
                                       NE * 128 / 4, 4);
  edge_coef<<<NE / 256, 256, 0, stream>>>(v2, se, te, aec, aev, aed, aecnt, coef2, rmax);
  edge_apply<<<NE, 128, 0, stream>>>(ZW2, aec, coef2, aed, aecnt, rmax, b2, zout);

  // ---- layer 3 (node): XW3p = x1 @ w3p (N padded to 256) ----
  wave_dot<<<NE * 64 / 256, 256, 0, stream>>>(zout, p3, v3, NE, 128);
  gemm_f4<false, 64, 256, 8><<<dim3(64, 8), 256, 0, stream>>>(x1, w3p, gpart, NN);
  reduce_part<<<512, 256, 0, stream>>>((const float4*)gpart, (float4*)XW3p,
                                       NN * 256 / 4, 8);
  node_apply<false><<<NN, 256, 0, stream>>>(XW3p, FOUTD, 256, v3, se, te, inc, icnt,
                                            avc, avv, avd, avcnt, b3, xout);
}